// Round 19
// baseline (100.465 us; speedup 1.0000x reference)
//
#include <hip/hip_runtime.h>
#include <hip/hip_bf16.h>
#include <stdint.h>

typedef __bf16 bf16;
typedef __bf16 bf16x8 __attribute__((ext_vector_type(8)));
typedef __bf16 bf16x4 __attribute__((ext_vector_type(4)));
typedef float f32x4 __attribute__((ext_vector_type(4)));

#define KDIM 768
#define NHEAD 12
#define HDIM 64
#define NTOK 1024
#define BATCH 8

// XOR swizzle for row-major [row][128B-row] LDS tiles (attention)
#define SWZ(row, b) ((b) ^ (((row) & 7) << 4))

__device__ __forceinline__ void gl_lds16(const bf16* g, bf16* l) {
    __builtin_amdgcn_global_load_lds((const __attribute__((address_space(1))) void*)g,
                                     (__attribute__((address_space(3))) void*)l, 16, 0, 0);
}

#define G_MFMA(a, b, c) __builtin_amdgcn_mfma_f32_16x16x32_bf16(a, b, c, 0, 0, 0)
#define VMW(N) asm volatile("s_waitcnt vmcnt(" #N ")" ::: "memory")

// ---------------- fp32 -> bf16 convert (all three tensors, one launch) ----------------
__global__ void k_cvt_all(const float* __restrict__ x, const float* __restrict__ wq,
                          const float* __restrict__ wp, bf16* __restrict__ xb,
                          bf16* __restrict__ wqb, bf16* __restrict__ wpb) {
    int b = blockIdx.x;
    const float* src;
    bf16* dst;
    int base;
    if (b < 6144)       { src = x;  dst = xb;  base = b; }
    else if (b < 7872)  { src = wq; dst = wqb; base = b - 6144; }
    else                { src = wp; dst = wpb; base = b - 7872; }
    int i = (base * 256 + threadIdx.x) * 4;
    float4 v = *(const float4*)(src + i);
    bf16x4 o;
    o[0] = (bf16)v.x; o[1] = (bf16)v.y; o[2] = (bf16)v.z; o[3] = (bf16)v.w;
    *(bf16x4*)(dst + i) = o;
}

// =====================================================================================
// BK=64 fine-phase GEMM (r15/r16-verified): 128(M) x 192(N) x K, 12 K-tiles,
// 4 waves (2x2), per-wave 64x96 (acc[4][6], 48 MFMA/tile). 2-slot LDS (80KB,
// 2 blocks/CU). All staging writes target slot s^1 -> NO mid-tile barrier; ONE
// vmcnt(0)+barrier per 48-MFMA tile. 128B LDS rows, XOR swizzle byte^=(row&7)<<4,
// pre-swizzled global source for the lane-linear global_load_lds destination.
// =====================================================================================

#define TILE64(S, kt) do {                                                      \
    const char* A8 = (const char*)sA[S];                                        \
    const char* B8 = (const char*)sB[S];                                        \
    bf16x8 af[4], bfr[6];                                                       \
    _Pragma("unroll")                                                           \
    for (int m = 0; m < 4; ++m)                                                 \
        af[m] = *(const bf16x8*)(A8 + (wr * 64 + m * 16 + lr) * 128 + k0off);   \
    _Pragma("unroll")                                                           \
    for (int n = 0; n < 6; ++n)                                                 \
        bfr[n] = *(const bf16x8*)(B8 + (wc * 96 + n * 16 + lr) * 128 + k0off);  \
    if ((kt) < 11) {                                                            \
        const bf16* p_ = Ast + (size_t)((kt) + 1) * 64;                         \
        gl_lds16(p_,                      &sA[(S) ^ 1][t * 8]);                 \
        gl_lds16(p_ + (size_t)32 * KDIM,  &sA[(S) ^ 1][t * 8 + 2048]);          \
        gl_lds16(p_ + (size_t)64 * KDIM,  &sA[(S) ^ 1][t * 8 + 4096]);          \
        gl_lds16(p_ + (size_t)96 * KDIM,  &sA[(S) ^ 1][t * 8 + 6144]);          \
    }                                                                           \
    __builtin_amdgcn_s_setprio(1);                                              \
    _Pragma("unroll")                                                           \
    for (int m = 0; m < 4; ++m)                                                 \
        _Pragma("unroll")                                                       \
        for (int n = 0; n < 6; ++n)                                             \
            acc[m][n] = G_MFMA(af[m], bfr[n], acc[m][n]);                       \
    __builtin_amdgcn_s_setprio(0);                                              \
    _Pragma("unroll")                                                           \
    for (int m = 0; m < 4; ++m)                                                 \
        af[m] = *(const bf16x8*)(A8 + (wr * 64 + m * 16 + lr) * 128 + k1off);   \
    _Pragma("unroll")                                                           \
    for (int n = 0; n < 6; ++n)                                                 \
        bfr[n] = *(const bf16x8*)(B8 + (wc * 96 + n * 16 + lr) * 128 + k1off);  \
    if ((kt) < 11) {                                                            \
        const bf16* p_ = Wst + (size_t)((kt) + 1) * 64;                         \
        gl_lds16(p_,                       &sB[(S) ^ 1][t * 8]);                \
        gl_lds16(p_ + (size_t)32 * KDIM,   &sB[(S) ^ 1][t * 8 + 2048]);         \
        gl_lds16(p_ + (size_t)64 * KDIM,   &sB[(S) ^ 1][t * 8 + 4096]);         \
        gl_lds16(p_ + (size_t)96 * KDIM,   &sB[(S) ^ 1][t * 8 + 6144]);         \
        gl_lds16(p_ + (size_t)128 * KDIM,  &sB[(S) ^ 1][t * 8 + 8192]);         \
        gl_lds16(p_ + (size_t)160 * KDIM,  &sB[(S) ^ 1][t * 8 + 10240]);        \
    }                                                                           \
    __builtin_amdgcn_s_setprio(1);                                              \
    _Pragma("unroll")                                                           \
    for (int m = 0; m < 4; ++m)                                                 \
        _Pragma("unroll")                                                       \
        for (int n = 0; n < 6; ++n)                                             \
            acc[m][n] = G_MFMA(af[m], bfr[n], acc[m][n]);                       \
    __builtin_amdgcn_s_setprio(0);                                              \
    VMW(0);                                                                     \
    __builtin_amdgcn_s_barrier();                                               \
} while (0)

#define GEMM64_PRE(A_PTR, W_PTR)                                                \
    const int t = threadIdx.x;                                                  \
    const int lane = t & 63;                                                    \
    const int wv = t >> 6;                                                      \
    const int wr = wv >> 1, wc = wv & 1;                                        \
    const int lr = lane & 15, lg = lane >> 4;                                   \
    const int xorb = (lr & 7) << 4;                                             \
    const int k0off = (lg << 4) ^ xorb;                                         \
    const int k1off = (64 + (lg << 4)) ^ xorb;                                  \
    const int spos = ((t & 7) ^ ((t >> 3) & 7)) * 8;                            \
    const int bm = blockIdx.x, bn = blockIdx.y;                                 \
    const bf16* Ast = (A_PTR) + (size_t)(bm * 128 + (t >> 3)) * KDIM + spos;    \
    const bf16* Wst = (W_PTR) + (size_t)(bn * 192 + (t >> 3)) * KDIM + spos;    \
    f32x4 acc[4][6] = {};                                                       \
    gl_lds16(Ast,                      &sA[0][t * 8]);                          \
    gl_lds16(Ast + (size_t)32 * KDIM,  &sA[0][t * 8 + 2048]);                   \
    gl_lds16(Ast + (size_t)64 * KDIM,  &sA[0][t * 8 + 4096]);                   \
    gl_lds16(Ast + (size_t)96 * KDIM,  &sA[0][t * 8 + 6144]);                   \
    gl_lds16(Wst,                       &sB[0][t * 8]);                         \
    gl_lds16(Wst + (size_t)32 * KDIM,   &sB[0][t * 8 + 2048]);                  \
    gl_lds16(Wst + (size_t)64 * KDIM,   &sB[0][t * 8 + 4096]);                  \
    gl_lds16(Wst + (size_t)96 * KDIM,   &sB[0][t * 8 + 6144]);                  \
    gl_lds16(Wst + (size_t)128 * KDIM,  &sB[0][t * 8 + 8192]);                  \
    gl_lds16(Wst + (size_t)160 * KDIM,  &sB[0][t * 8 + 10240]);                 \
    VMW(0);                                                                     \
    __builtin_amdgcn_s_barrier();                                               \
    _Pragma("unroll 1")                                                         \
    for (int g = 0; g < 6; ++g) {                                               \
        TILE64(0, g * 2);                                                       \
        TILE64(1, g * 2 + 1);                                                   \
    }

__global__ __launch_bounds__(256, 2) void k_gemm_qkv(
    const bf16* __restrict__ A, const bf16* __restrict__ W,
    bf16* __restrict__ qb, bf16* __restrict__ kb, bf16* __restrict__ vb)
{
    __shared__ __attribute__((aligned(16))) bf16 sA[2][8192];    // 128 rows x 64
    __shared__ __attribute__((aligned(16))) bf16 sB[2][12288];   // 192 rows x 64
    GEMM64_PRE(A, W);

    const float QSC = 0.18033688011112042f;  // 0.125 * log2(e) folded into q
#pragma unroll
    for (int n = 0; n < 6; ++n) {
        int o = bn * 192 + wc * 96 + n * 16 + lr;
        int s = o / 768;
        int rem = o - s * 768;
        int head = rem >> 6;
        int d = o & 63;
        bf16* dst = (s == 0) ? qb : ((s == 1) ? kb : vb);
        float sc = (s == 0) ? QSC : 1.0f;
#pragma unroll
        for (int m = 0; m < 4; ++m) {
            int grow = bm * 128 + wr * 64 + m * 16 + lg * 4;
            int bidx = grow >> 10;
            int tok = grow & 1023;
            size_t base = (((size_t)bidx * NHEAD + head) * NTOK + tok) * HDIM + d;
#pragma unroll
            for (int r = 0; r < 4; ++r)
                dst[base + (size_t)r * HDIM] = (bf16)(acc[m][n][r] * sc);
        }
    }
}

__global__ __launch_bounds__(256, 2) void k_gemm_proj(
    const bf16* __restrict__ A, const bf16* __restrict__ W,
    const float* __restrict__ bias, float* __restrict__ out)
{
    __shared__ __attribute__((aligned(16))) bf16 sA[2][8192];
    __shared__ __attribute__((aligned(16))) bf16 sB[2][12288];
    GEMM64_PRE(A, W);

#pragma unroll
    for (int n = 0; n < 6; ++n) {
        int col = bn * 192 + wc * 96 + n * 16 + lr;
        float bv = bias[col];
#pragma unroll
        for (int m = 0; m < 4; ++m) {
            int grow = bm * 128 + wr * 64 + m * 16 + lg * 4;
#pragma unroll
            for (int r = 0; r < 4; ++r)
                out[(size_t)(grow + r) * KDIM + col] = acc[m][n][r] + bv;
        }
    }
}

// =====================================================================================
// Banded flash attention — K DIRECT FROM GLOBAL (L2-hot: 12 bh per XCD -> 1.5MB K
// per XCD L2); only V^T staged in LDS (24KB total -> higher occupancy). K frag loads
// are issued BEFORE the V-barrier (no LDS dependency) so barrier latency + compiler
// per-reg vmcnt hide the L2 round trip. 64-key steps, static-max softmax.
// =====================================================================================
__global__ __launch_bounds__(256) void k_attn(
    const bf16* __restrict__ qbuf, const bf16* __restrict__ kbuf,
    const bf16* __restrict__ vbuf, bf16* __restrict__ ob)
{
    const int x = blockIdx.x;
    const int sub = x >> 3;
    const int bh = (x & 7) * 12 + (sub >> 4);   // 12 bh per XCD
    const int qblk = sub & 15;                   // == h_q
    const int head = bh % NHEAD, bidx = bh / NHEAD;
    const bf16* Q  = qbuf + (size_t)bh * NTOK * HDIM;
    const bf16* Kp = kbuf + (size_t)bh * NTOK * HDIM;
    const bf16* Vp = vbuf + (size_t)bh * NTOK * HDIM;

    const int t = threadIdx.x, lane = t & 63, wv = t >> 6;
    const int lr = lane & 15, lg = lane >> 4, lkb = lg * 8;

    __shared__ bf16 vT[2][64 * 64];   // [d][key], swizzled (16KB)
    __shared__ bf16 pls[4][16 * 64];  // per-wave P [q][key], swizzled (8KB)

    {
        bf16x8 z = {};
        *(bf16x8*)&pls[wv][lane * 16] = z;
        *(bf16x8*)&pls[wv][lane * 16 + 8] = z;
    }

    bf16x8 qf[2];
#pragma unroll
    for (int ks = 0; ks < 2; ++ks)
        qf[ks] = *(const bf16x8*)(Q + (size_t)(qblk * 64 + wv * 16 + lr) * HDIM + ks * 32 + lkb);

    f32x4 acc[4] = {};
    float lrow[4] = {0.f, 0.f, 0.f, 0.f};

    const int kh0 = (qblk - 3 < 0) ? 0 : qblk - 3;
    const int kh1 = (qblk + 3 > 15) ? 15 : qblk + 3;

    const int sj = t >> 2;
    const int sd = (t & 3) * 16;

    const bf16* vs0 = Vp + (size_t)(kh0 * 64 + sj) * HDIM + sd;
    bf16x8 gv0 = *(const bf16x8*)vs0, gv1 = *(const bf16x8*)(vs0 + 8);

    char* pb8 = (char*)pls[wv];
    const int wq0 = wv * 16 + lg * 4;
    int cur = 0;

    for (int kh = kh0; kh <= kh1; ++kh) {
        char* vb8 = (char*)vT[cur];
        // ---- stage V^T (scatter transpose, swizzled) ----
#pragma unroll
        for (int ii = 0; ii < 8; ++ii) {
            int d = sd + ii;
            *(bf16*)(vb8 + SWZ(d, (d << 7) + (sj << 1))) = gv0[ii];
        }
#pragma unroll
        for (int ii = 0; ii < 8; ++ii) {
            int d = sd + 8 + ii;
            *(bf16*)(vb8 + SWZ(d, (d << 7) + (sj << 1))) = gv1[ii];
        }
        // ---- K frags for THIS kh direct from global (no LDS dep -> pre-barrier) ----
        bf16x8 kfr[3][2];
#pragma unroll
        for (int jj = 0; jj < 3; ++jj) {
            int j = wv - 1 + jj;
            if (j >= 0 && j <= 3) {        // wave-uniform
                const bf16* kr = Kp + (size_t)(kh * 64 + j * 16 + lr) * HDIM + lkb;
                kfr[jj][0] = *(const bf16x8*)(kr);
                kfr[jj][1] = *(const bf16x8*)(kr + 32);
            }
        }
        // ---- prefetch next kh's V (in flight across the barrier) ----
        if (kh < kh1) {
            const bf16* vn = Vp + (size_t)((kh + 1) * 64 + sj) * HDIM + sd;
            gv0 = *(const bf16x8*)vn; gv1 = *(const bf16x8*)(vn + 8);
        }
        asm volatile("s_waitcnt lgkmcnt(0)" ::: "memory");
        __builtin_amdgcn_s_barrier();

        // ---- QK^T + P = exp2(s) (static max), accumulate row sums, write P ----
        float psum[4] = {0.f, 0.f, 0.f, 0.f};
#pragma unroll
        for (int jj = 0; jj < 3; ++jj) {
            int j = wv - 1 + jj;
            if (j >= 0 && j <= 3) {        // wave-uniform
                int key = j * 16 + lr;
                f32x4 sv = {};
                sv = G_MFMA(qf[0], kfr[jj][0], sv);
                sv = G_MFMA(qf[1], kfr[jj][1], sv);
#pragma unroll
                for (int r = 0; r < 4; ++r) {
                    int dw = wq0 + r - key;
                    float p = (dw >= -5 && dw <= 5) ? exp2f(sv[r]) : 0.0f;
                    psum[r] += p;
                    int row = lg * 4 + r;
                    *(bf16*)(pb8 + SWZ(row, row * 128 + key * 2)) = (bf16)p;
                }
            }
        }
#pragma unroll
        for (int r = 0; r < 4; ++r) lrow[r] += psum[r];

        // ---- PV: A = P[16x64], B = V^T ----
        bf16x8 pf0 = *(const bf16x8*)(pb8 + SWZ(lr, lr * 128 + lg * 16));
        bf16x8 pf1 = *(const bf16x8*)(pb8 + SWZ(lr, lr * 128 + 64 + lg * 16));
#pragma unroll
        for (int dt = 0; dt < 4; ++dt) {
            int vrow = dt * 16 + lr;
            bf16x8 vf0 = *(const bf16x8*)(vb8 + SWZ(vrow, vrow * 128 + lg * 16));
            bf16x8 vf1 = *(const bf16x8*)(vb8 + SWZ(vrow, vrow * 128 + 64 + lg * 16));
            acc[dt] = G_MFMA(pf0, vf0, acc[dt]);
            acc[dt] = G_MFMA(pf1, vf1, acc[dt]);
        }
        cur ^= 1;
    } // kh

    // ---- finalize ----
#pragma unroll
    for (int off = 1; off < 16; off <<= 1)
#pragma unroll
        for (int r = 0; r < 4; ++r) lrow[r] += __shfl_xor(lrow[r], off);

#pragma unroll
    for (int r = 0; r < 4; ++r) {
        float inv = 1.0f / lrow[r];
        int tok = qblk * 64 + wv * 16 + lg * 4 + r;
        size_t rowbase = ((size_t)bidx * NTOK + tok) * KDIM + head * HDIM;
#pragma unroll
        for (int dt = 0; dt < 4; ++dt)
            ob[rowbase + dt * 16 + lr] = (bf16)(acc[dt][r] * inv);
    }
}

// ---------------- launcher ----------------
extern "C" void kernel_launch(void* const* d_in, const int* in_sizes, int n_in,
                              void* d_out, int out_size, void* d_ws, size_t ws_size,
                              hipStream_t stream) {
    const float* x      = (const float*)d_in[0];
    const float* w_qkv  = (const float*)d_in[1];
    const float* w_proj = (const float*)d_in[2];
    const float* b_proj = (const float*)d_in[3];
    float* out = (float*)d_out;

    char* ws = (char*)d_ws;
    bf16* xb  = (bf16*)(ws);                  // 8192*768*2   = 12582912
    bf16* wqb = (bf16*)(ws + 12582912);       // 2304*768*2   =  3538944
    bf16* wpb = (bf16*)(ws + 16121856);       // 768*768*2    =  1179648
    bf16* qb  = (bf16*)(ws + 17301504);       // 96*1024*64*2 = 12582912
    bf16* kb  = (bf16*)(ws + 29884416);
    bf16* vb  = (bf16*)(ws + 42467328);
    bf16* aob = (bf16*)(ws + 55050240);       // attn out bf16 [8192][768]

    hipLaunchKernelGGL(k_cvt_all, dim3(8448), dim3(256), 0, stream, x, w_qkv, w_proj, xb, wqb, wpb);
    hipLaunchKernelGGL(k_gemm_qkv, dim3(64, 12), dim3(256), 0, stream, xb, wqb, qb, kb, vb);
    hipLaunchKernelGGL(k_attn,     dim3(1536), dim3(256), 0, stream, qb, kb, vb, aob);
    hipLaunchKernelGGL(k_gemm_proj, dim3(64, 4), dim3(256), 0, stream, aob, wpb, b_proj, out);
}

// Round 20
// 91.189 us; speedup vs baseline: 1.1017x; 1.1017x over previous
//
#include <hip/hip_runtime.h>
#include <hip/hip_bf16.h>
#include <stdint.h>

typedef __bf16 bf16;
typedef __bf16 bf16x8 __attribute__((ext_vector_type(8)));
typedef __bf16 bf16x4 __attribute__((ext_vector_type(4)));
typedef float f32x4 __attribute__((ext_vector_type(4)));

#define KDIM 768
#define NHEAD 12
#define HDIM 64
#define NTOK 1024
#define BATCH 8

// XOR swizzle for row-major [row][128B-row] LDS tiles (attention)
#define SWZ(row, b) ((b) ^ (((row) & 7) << 4))

__device__ __forceinline__ void gl_lds16(const bf16* g, bf16* l) {
    __builtin_amdgcn_global_load_lds((const __attribute__((address_space(1))) void*)g,
                                     (__attribute__((address_space(3))) void*)l, 16, 0, 0);
}

#define G_MFMA(a, b, c) __builtin_amdgcn_mfma_f32_16x16x32_bf16(a, b, c, 0, 0, 0)
#define VMW(N) asm volatile("s_waitcnt vmcnt(" #N ")" ::: "memory")

// ---------------- fp32 -> bf16 convert (all three tensors, one launch) ----------------
__global__ void k_cvt_all(const float* __restrict__ x, const float* __restrict__ wq,
                          const float* __restrict__ wp, bf16* __restrict__ xb,
                          bf16* __restrict__ wqb, bf16* __restrict__ wpb) {
    int b = blockIdx.x;
    const float* src;
    bf16* dst;
    int base;
    if (b < 6144)       { src = x;  dst = xb;  base = b; }
    else if (b < 7872)  { src = wq; dst = wqb; base = b - 6144; }
    else                { src = wp; dst = wpb; base = b - 7872; }
    int i = (base * 256 + threadIdx.x) * 4;
    float4 v = *(const float4*)(src + i);
    bf16x4 o;
    o[0] = (bf16)v.x; o[1] = (bf16)v.y; o[2] = (bf16)v.z; o[3] = (bf16)v.w;
    *(bf16x4*)(dst + i) = o;
}

// =====================================================================================
// BK=64 fine-phase GEMM (r15/r16-verified): 128(M) x 192(N) x K, 12 K-tiles,
// 4 waves (2x2), per-wave 64x96 (acc[4][6], 48 MFMA/tile). 2-slot LDS (80KB,
// 2 blocks/CU). All staging writes target slot s^1 -> NO mid-tile barrier; ONE
// vmcnt(0)+barrier per 48-MFMA tile. 128B LDS rows, XOR swizzle byte^=(row&7)<<4,
// pre-swizzled global source for the lane-linear global_load_lds destination.
// =====================================================================================

#define TILE64(S, kt) do {                                                      \
    const char* A8 = (const char*)sA[S];                                        \
    const char* B8 = (const char*)sB[S];                                        \
    bf16x8 af[4], bfr[6];                                                       \
    _Pragma("unroll")                                                           \
    for (int m = 0; m < 4; ++m)                                                 \
        af[m] = *(const bf16x8*)(A8 + (wr * 64 + m * 16 + lr) * 128 + k0off);   \
    _Pragma("unroll")                                                           \
    for (int n = 0; n < 6; ++n)                                                 \
        bfr[n] = *(const bf16x8*)(B8 + (wc * 96 + n * 16 + lr) * 128 + k0off);  \
    if ((kt) < 11) {                                                            \
        const bf16* p_ = Ast + (size_t)((kt) + 1) * 64;                         \
        gl_lds16(p_,                      &sA[(S) ^ 1][t * 8]);                 \
        gl_lds16(p_ + (size_t)32 * KDIM,  &sA[(S) ^ 1][t * 8 + 2048]);          \
        gl_lds16(p_ + (size_t)64 * KDIM,  &sA[(S) ^ 1][t * 8 + 4096]);          \
        gl_lds16(p_ + (size_t)96 * KDIM,  &sA[(S) ^ 1][t * 8 + 6144]);          \
    }                                                                           \
    __builtin_amdgcn_s_setprio(1);                                              \
    _Pragma("unroll")                                                           \
    for (int m = 0; m < 4; ++m)                                                 \
        _Pragma("unroll")                                                       \
        for (int n = 0; n < 6; ++n)                                             \
            acc[m][n] = G_MFMA(af[m], bfr[n], acc[m][n]);                       \
    __builtin_amdgcn_s_setprio(0);                                              \
    _Pragma("unroll")                                                           \
    for (int m = 0; m < 4; ++m)                                                 \
        af[m] = *(const bf16x8*)(A8 + (wr * 64 + m * 16 + lr) * 128 + k1off);   \
    _Pragma("unroll")                                                           \
    for (int n = 0; n < 6; ++n)                                                 \
        bfr[n] = *(const bf16x8*)(B8 + (wc * 96 + n * 16 + lr) * 128 + k1off);  \
    if ((kt) < 11) {                                                            \
        const bf16* p_ = Wst + (size_t)((kt) + 1) * 64;                         \
        gl_lds16(p_,                       &sB[(S) ^ 1][t * 8]);                \
        gl_lds16(p_ + (size_t)32 * KDIM,   &sB[(S) ^ 1][t * 8 + 2048]);         \
        gl_lds16(p_ + (size_t)64 * KDIM,   &sB[(S) ^ 1][t * 8 + 4096]);         \
        gl_lds16(p_ + (size_t)96 * KDIM,   &sB[(S) ^ 1][t * 8 + 6144]);         \
        gl_lds16(p_ + (size_t)128 * KDIM,  &sB[(S) ^ 1][t * 8 + 8192]);         \
        gl_lds16(p_ + (size_t)160 * KDIM,  &sB[(S) ^ 1][t * 8 + 10240]);        \
    }                                                                           \
    __builtin_amdgcn_s_setprio(1);                                              \
    _Pragma("unroll")                                                           \
    for (int m = 0; m < 4; ++m)                                                 \
        _Pragma("unroll")                                                       \
        for (int n = 0; n < 6; ++n)                                             \
            acc[m][n] = G_MFMA(af[m], bfr[n], acc[m][n]);                       \
    __builtin_amdgcn_s_setprio(0);                                              \
    VMW(0);                                                                     \
    __builtin_amdgcn_s_barrier();                                               \
} while (0)

#define GEMM64_PRE(A_PTR, W_PTR)                                                \
    const int t = threadIdx.x;                                                  \
    const int lane = t & 63;                                                    \
    const int wv = t >> 6;                                                      \
    const int wr = wv >> 1, wc = wv & 1;                                        \
    const int lr = lane & 15, lg = lane >> 4;                                   \
    const int xorb = (lr & 7) << 4;                                             \
    const int k0off = (lg << 4) ^ xorb;                                         \
    const int k1off = (64 + (lg << 4)) ^ xorb;                                  \
    const int spos = ((t & 7) ^ ((t >> 3) & 7)) * 8;                            \
    const int bm = blockIdx.x, bn = blockIdx.y;                                 \
    const bf16* Ast = (A_PTR) + (size_t)(bm * 128 + (t >> 3)) * KDIM + spos;    \
    const bf16* Wst = (W_PTR) + (size_t)(bn * 192 + (t >> 3)) * KDIM + spos;    \
    f32x4 acc[4][6] = {};                                                       \
    gl_lds16(Ast,                      &sA[0][t * 8]);                          \
    gl_lds16(Ast + (size_t)32 * KDIM,  &sA[0][t * 8 + 2048]);                   \
    gl_lds16(Ast + (size_t)64 * KDIM,  &sA[0][t * 8 + 4096]);                   \
    gl_lds16(Ast + (size_t)96 * KDIM,  &sA[0][t * 8 + 6144]);                   \
    gl_lds16(Wst,                       &sB[0][t * 8]);                         \
    gl_lds16(Wst + (size_t)32 * KDIM,   &sB[0][t * 8 + 2048]);                  \
    gl_lds16(Wst + (size_t)64 * KDIM,   &sB[0][t * 8 + 4096]);                  \
    gl_lds16(Wst + (size_t)96 * KDIM,   &sB[0][t * 8 + 6144]);                  \
    gl_lds16(Wst + (size_t)128 * KDIM,  &sB[0][t * 8 + 8192]);                  \
    gl_lds16(Wst + (size_t)160 * KDIM,  &sB[0][t * 8 + 10240]);                 \
    VMW(0);                                                                     \
    __builtin_amdgcn_s_barrier();                                               \
    _Pragma("unroll 1")                                                         \
    for (int g = 0; g < 6; ++g) {                                               \
        TILE64(0, g * 2);                                                       \
        TILE64(1, g * 2 + 1);                                                   \
    }

__global__ __launch_bounds__(256, 2) void k_gemm_qkv(
    const bf16* __restrict__ A, const bf16* __restrict__ W,
    bf16* __restrict__ qb, bf16* __restrict__ kb, bf16* __restrict__ vb)
{
    __shared__ __attribute__((aligned(16))) bf16 sA[2][8192];    // 128 rows x 64
    __shared__ __attribute__((aligned(16))) bf16 sB[2][12288];   // 192 rows x 64
    GEMM64_PRE(A, W);

    const float QSC = 0.18033688011112042f;  // 0.125 * log2(e) folded into q
#pragma unroll
    for (int n = 0; n < 6; ++n) {
        int o = bn * 192 + wc * 96 + n * 16 + lr;
        int s = o / 768;
        int rem = o - s * 768;
        int head = rem >> 6;
        int d = o & 63;
        bf16* dst = (s == 0) ? qb : ((s == 1) ? kb : vb);
        float sc = (s == 0) ? QSC : 1.0f;
#pragma unroll
        for (int m = 0; m < 4; ++m) {
            int grow = bm * 128 + wr * 64 + m * 16 + lg * 4;
            int bidx = grow >> 10;
            int tok = grow & 1023;
            size_t base = (((size_t)bidx * NHEAD + head) * NTOK + tok) * HDIM + d;
#pragma unroll
            for (int r = 0; r < 4; ++r)
                dst[base + (size_t)r * HDIM] = (bf16)(acc[m][n][r] * sc);
        }
    }
}

__global__ __launch_bounds__(256, 2) void k_gemm_proj(
    const bf16* __restrict__ A, const bf16* __restrict__ W,
    const float* __restrict__ bias, float* __restrict__ out)
{
    __shared__ __attribute__((aligned(16))) bf16 sA[2][8192];
    __shared__ __attribute__((aligned(16))) bf16 sB[2][12288];
    GEMM64_PRE(A, W);

#pragma unroll
    for (int n = 0; n < 6; ++n) {
        int col = bn * 192 + wc * 96 + n * 16 + lr;
        float bv = bias[col];
#pragma unroll
        for (int m = 0; m < 4; ++m) {
            int grow = bm * 128 + wr * 64 + m * 16 + lg * 4;
#pragma unroll
            for (int r = 0; r < 4; ++r)
                out[(size_t)(grow + r) * KDIM + col] = acc[m][n][r] + bv;
        }
    }
}

// =====================================================================================
// Banded flash attention (r16-exact: 256 threads, 64-key steps, static-max softmax)
// =====================================================================================
__global__ __launch_bounds__(256) void k_attn(
    const bf16* __restrict__ qbuf, const bf16* __restrict__ kbuf,
    const bf16* __restrict__ vbuf, bf16* __restrict__ ob)
{
    const int x = blockIdx.x;
    const int sub = x >> 3;
    const int bh = (x & 7) * 12 + (sub >> 4);   // 12 bh per XCD
    const int qblk = sub & 15;                   // == h_q
    const int head = bh % NHEAD, bidx = bh / NHEAD;
    const bf16* Q  = qbuf + (size_t)bh * NTOK * HDIM;
    const bf16* Kp = kbuf + (size_t)bh * NTOK * HDIM;
    const bf16* Vp = vbuf + (size_t)bh * NTOK * HDIM;

    const int t = threadIdx.x, lane = t & 63, wv = t >> 6;
    const int lr = lane & 15, lg = lane >> 4, lkb = lg * 8;

    __shared__ bf16 Ks[2][64 * 64];   // [key][d], swizzled
    __shared__ bf16 vT[2][64 * 64];   // [d][key], swizzled
    __shared__ bf16 pls[4][16 * 64];  // per-wave P [q][key], swizzled

    {
        bf16x8 z = {};
        *(bf16x8*)&pls[wv][lane * 16] = z;
        *(bf16x8*)&pls[wv][lane * 16 + 8] = z;
    }

    bf16x8 qf[2];
#pragma unroll
    for (int ks = 0; ks < 2; ++ks)
        qf[ks] = *(const bf16x8*)(Q + (size_t)(qblk * 64 + wv * 16 + lr) * HDIM + ks * 32 + lkb);

    f32x4 acc[4] = {};
    float lrow[4] = {0.f, 0.f, 0.f, 0.f};

    const int kh0 = (qblk - 3 < 0) ? 0 : qblk - 3;
    const int kh1 = (qblk + 3 > 15) ? 15 : qblk + 3;

    const int sj = t >> 2;
    const int sd = (t & 3) * 16;

    const bf16* ks0 = Kp + (size_t)(kh0 * 64 + sj) * HDIM + sd;
    const bf16* vs0 = Vp + (size_t)(kh0 * 64 + sj) * HDIM + sd;
    bf16x8 gk0 = *(const bf16x8*)ks0, gk1 = *(const bf16x8*)(ks0 + 8);
    bf16x8 gv0 = *(const bf16x8*)vs0, gv1 = *(const bf16x8*)(vs0 + 8);

    char* pb8 = (char*)pls[wv];
    const int wq0 = wv * 16 + lg * 4;
    int cur = 0;

    for (int kh = kh0; kh <= kh1; ++kh) {
        char* kb8 = (char*)Ks[cur];
        char* vb8 = (char*)vT[cur];
        {
            int kbo = sj * 128 + sd * 2;
            *(bf16x8*)(kb8 + SWZ(sj, kbo)) = gk0;
            *(bf16x8*)(kb8 + SWZ(sj, kbo + 16)) = gk1;
        }
#pragma unroll
        for (int ii = 0; ii < 8; ++ii) {
            int d = sd + ii;
            *(bf16*)(vb8 + SWZ(d, (d << 7) + (sj << 1))) = gv0[ii];
        }
#pragma unroll
        for (int ii = 0; ii < 8; ++ii) {
            int d = sd + 8 + ii;
            *(bf16*)(vb8 + SWZ(d, (d << 7) + (sj << 1))) = gv1[ii];
        }
        if (kh < kh1) {
            const bf16* kn = Kp + (size_t)((kh + 1) * 64 + sj) * HDIM + sd;
            const bf16* vn = Vp + (size_t)((kh + 1) * 64 + sj) * HDIM + sd;
            gk0 = *(const bf16x8*)kn; gk1 = *(const bf16x8*)(kn + 8);
            gv0 = *(const bf16x8*)vn; gv1 = *(const bf16x8*)(vn + 8);
        }
        asm volatile("s_waitcnt lgkmcnt(0)" ::: "memory");
        __builtin_amdgcn_s_barrier();

        // ---- QK^T + P = exp2(s) (static max), accumulate row sums, write P ----
        float psum[4] = {0.f, 0.f, 0.f, 0.f};
#pragma unroll
        for (int jj = 0; jj < 3; ++jj) {
            int j = wv - 1 + jj;
            if (j >= 0 && j <= 3) {        // wave-uniform
                int key = j * 16 + lr;
                int kbase = key * 128;
                bf16x8 kf0 = *(const bf16x8*)(kb8 + SWZ(key, kbase + lg * 16));
                bf16x8 kf1 = *(const bf16x8*)(kb8 + SWZ(key, kbase + 64 + lg * 16));
                f32x4 sv = {};
                sv = G_MFMA(qf[0], kf0, sv);
                sv = G_MFMA(qf[1], kf1, sv);
#pragma unroll
                for (int r = 0; r < 4; ++r) {
                    int dw = wq0 + r - key;
                    float p = (dw >= -5 && dw <= 5) ? exp2f(sv[r]) : 0.0f;
                    psum[r] += p;
                    int row = lg * 4 + r;
                    *(bf16*)(pb8 + SWZ(row, row * 128 + key * 2)) = (bf16)p;
                }
            }
        }
#pragma unroll
        for (int r = 0; r < 4; ++r) lrow[r] += psum[r];

        // ---- PV: A = P[16x64], B = V^T ----
        bf16x8 pf0 = *(const bf16x8*)(pb8 + SWZ(lr, lr * 128 + lg * 16));
        bf16x8 pf1 = *(const bf16x8*)(pb8 + SWZ(lr, lr * 128 + 64 + lg * 16));
#pragma unroll
        for (int dt = 0; dt < 4; ++dt) {
            int vrow = dt * 16 + lr;
            bf16x8 vf0 = *(const bf16x8*)(vb8 + SWZ(vrow, vrow * 128 + lg * 16));
            bf16x8 vf1 = *(const bf16x8*)(vb8 + SWZ(vrow, vrow * 128 + 64 + lg * 16));
            acc[dt] = G_MFMA(pf0, vf0, acc[dt]);
            acc[dt] = G_MFMA(pf1, vf1, acc[dt]);
        }
        cur ^= 1;
    } // kh

    // ---- finalize ----
#pragma unroll
    for (int off = 1; off < 16; off <<= 1)
#pragma unroll
        for (int r = 0; r < 4; ++r) lrow[r] += __shfl_xor(lrow[r], off);

#pragma unroll
    for (int r = 0; r < 4; ++r) {
        float inv = 1.0f / lrow[r];
        int tok = qblk * 64 + wv * 16 + lg * 4 + r;
        size_t rowbase = ((size_t)bidx * NTOK + tok) * KDIM + head * HDIM;
#pragma unroll
        for (int dt = 0; dt < 4; ++dt)
            ob[rowbase + dt * 16 + lr] = (bf16)(acc[dt][r] * inv);
    }
}

// ---------------- launcher ----------------
extern "C" void kernel_launch(void* const* d_in, const int* in_sizes, int n_in,
                              void* d_out, int out_size, void* d_ws, size_t ws_size,
                              hipStream_t stream) {
    const float* x      = (const float*)d_in[0];
    const float* w_qkv  = (const float*)d_in[1];
    const float* w_proj = (const float*)d_in[2];
    const float* b_proj = (const float*)d_in[3];
    float* out = (float*)d_out;

    char* ws = (char*)d_ws;
    bf16* xb  = (bf16*)(ws);                  // 8192*768*2   = 12582912
    bf16* wqb = (bf16*)(ws + 12582912);       // 2304*768*2   =  3538944
    bf16* wpb = (bf16*)(ws + 16121856);       // 768*768*2    =  1179648
    bf16* qb  = (bf16*)(ws + 17301504);       // 96*1024*64*2 = 12582912
    bf16* kb  = (bf16*)(ws + 29884416);
    bf16* vb  = (bf16*)(ws + 42467328);
    bf16* aob = (bf16*)(ws + 55050240);       // attn out bf16 [8192][768]

    hipLaunchKernelGGL(k_cvt_all, dim3(8448), dim3(256), 0, stream, x, w_qkv, w_proj, xb, wqb, wpb);
    hipLaunchKernelGGL(k_gemm_qkv, dim3(64, 12), dim3(256), 0, stream, xb, wqb, qb, kb, vb);
    hipLaunchKernelGGL(k_attn,     dim3(1536), dim3(256), 0, stream, qb, kb, vb, aob);
    hipLaunchKernelGGL(k_gemm_proj, dim3(64, 4), dim3(256), 0, stream, aob, wpb, b_proj, out);
}